// Round 6
// baseline (169.227 us; speedup 1.0000x reference)
//
#include <hip/hip_runtime.h>
#include <hip/hip_bf16.h>
#include <stdint.h>

#define M_TOT 16384
#define N_TOT 2048
#define K_TOT 2048
#define NT 32            // K-tiles of BK=64

typedef __attribute__((ext_vector_type(8))) short bf16x8;
typedef __attribute__((ext_vector_type(4))) float f32x4;

__device__ __forceinline__ ushort f32_to_bf16_rne(float f) {
    uint32_t u = __float_as_uint(f);
    uint32_t r = (u + 0x7fffu + ((u >> 16) & 1u)) >> 16;
    return (ushort)r;
}

__device__ __forceinline__ void async_copy16(const void* gptr, void* lptr) {
    __builtin_amdgcn_global_load_lds(
        (const __attribute__((address_space(1))) uint32_t*)gptr,
        (__attribute__((address_space(3))) uint32_t*)lptr,
        16, 0, 0);
}

// ---------------------------------------------------------------------------
// Fake-quantize x: per (row, 32-col) block, symmetric int8 -> bf16.
// ---------------------------------------------------------------------------
__global__ void quant_x_kernel(const float* __restrict__ x, ushort* __restrict__ qx) {
    const int tid = blockIdx.x * 256 + threadIdx.x;
    const float4 v = ((const float4*)x)[tid];
    float m = fmaxf(fmaxf(fabsf(v.x), fabsf(v.y)), fmaxf(fabsf(v.z), fabsf(v.w)));
    m = fmaxf(m, __shfl_xor(m, 1));
    m = fmaxf(m, __shfl_xor(m, 2));
    m = fmaxf(m, __shfl_xor(m, 4));
    const float s = (m > 0.f) ? (m / 127.f) : 1.f;
    const float q0 = fminf(fmaxf(rintf(v.x / s), -127.f), 127.f) * s;
    const float q1 = fminf(fmaxf(rintf(v.y / s), -127.f), 127.f) * s;
    const float q2 = fminf(fmaxf(rintf(v.z / s), -127.f), 127.f) * s;
    const float q3 = fminf(fmaxf(rintf(v.w / s), -127.f), 127.f) * s;
    ushort4 r;
    r.x = f32_to_bf16_rne(q0);
    r.y = f32_to_bf16_rne(q1);
    r.z = f32_to_bf16_rne(q2);
    r.w = f32_to_bf16_rne(q3);
    ((ushort4*)qx)[tid] = r;
}

// ---------------------------------------------------------------------------
// Fake-quantize weight (kept [Dout][Din] == B^T layout). 32x32 blocks.
// ---------------------------------------------------------------------------
__global__ void quant_w_kernel(const float* __restrict__ w, ushort* __restrict__ qw) {
    const int gtid = blockIdx.x * 256 + threadIdx.x;
    const int wid  = gtid >> 6;
    const int lane = gtid & 63;
    const int tn = wid >> 6;
    const int tk = wid & 63;
    const int row = tn * 32 + (lane >> 1);
    const int col = tk * 32 + ((lane & 1) << 4);
    const float* p = w + (size_t)row * K_TOT + col;
    const float4 v0 = ((const float4*)p)[0];
    const float4 v1 = ((const float4*)p)[1];
    const float4 v2 = ((const float4*)p)[2];
    const float4 v3 = ((const float4*)p)[3];
    float m = 0.f;
#define MAX4(V) m = fmaxf(m, fmaxf(fmaxf(fabsf(V.x), fabsf(V.y)), fmaxf(fabsf(V.z), fabsf(V.w))));
    MAX4(v0) MAX4(v1) MAX4(v2) MAX4(v3)
#undef MAX4
    #pragma unroll
    for (int off = 1; off < 64; off <<= 1) m = fmaxf(m, __shfl_xor(m, off));
    const float s = (m > 0.f) ? (m / 127.f) : 1.f;
    float vv[16] = {v0.x, v0.y, v0.z, v0.w, v1.x, v1.y, v1.z, v1.w,
                    v2.x, v2.y, v2.z, v2.w, v3.x, v3.y, v3.z, v3.w};
    union { ushort us[16]; uint4 q[2]; } o;
    #pragma unroll
    for (int i = 0; i < 16; ++i) {
        const float q = fminf(fmaxf(rintf(vv[i] / s), -127.f), 127.f) * s;
        o.us[i] = f32_to_bf16_rne(q);
    }
    uint4* dst = (uint4*)(qw + (size_t)row * K_TOT + col);
    dst[0] = o.q[0];
    dst[1] = o.q[1];
}

// ---------------------------------------------------------------------------
// 256x256 bf16 GEMM, flattened-read pipeline:
//   Every lgkm wait covers only reads issued >=1 phase earlier (they drain
//   under the previous MFMA burst).  bg(t+1) is read at END of p3 (after
//   MFMA q3, register-WAR enforced) and retired by p0's lgkmcnt(4).
//   Per-phase CU LDS work 768/384/384/768 cyc vs 620 MFMA -> overlappable.
//   2 barriers/tile; vmcnt(4)@p1 drains B(t+1); vmcnt(4)@p3 drains A(t+1).
// ---------------------------------------------------------------------------
#define LDSA(tb, row, colus) \
    (*(const bf16x8*)&As[tb][row][(colus) ^ (((row) & 7) << 3)])
#define LDSB(tb, row, colus) \
    (*(const bf16x8*)&Bs[tb][row][(colus) ^ (((row) & 7) << 3)])

#define STAGE_A(tb, hh, li, tt)                                                          \
    async_copy16(Agbase + (size_t)((hh) * 128 + (li) * 64) * K_TOT + (size_t)(tt) * 64,  \
                 (char*)&As[0][0][0] + (tb) * 32768 + (hh) * 16384 + (li) * 8192 + (wv << 10));
#define STAGE_B(tb, hh, li, tt)                                                          \
    async_copy16(Bgbase + (size_t)((hh) * 128 + (li) * 64) * K_TOT + (size_t)(tt) * 64,  \
                 (char*)&Bs[0][0][0] + (tb) * 32768 + (hh) * 16384 + (li) * 8192 + (wv << 10));
#define STAGE_A2(tb, hh, tt)  { STAGE_A(tb, hh, 0, tt) STAGE_A(tb, hh, 1, tt) }
#define STAGE_B2(tb, hh, tt)  { STAGE_B(tb, hh, 0, tt) STAGE_B(tb, hh, 1, tt) }

#define WAITLGKM4 { asm volatile("s_waitcnt lgkmcnt(4)" ::: "memory"); __builtin_amdgcn_sched_barrier(0); }
#define WAITLGKM0 { asm volatile("s_waitcnt lgkmcnt(0)" ::: "memory"); __builtin_amdgcn_sched_barrier(0); }

// read the 4 A-fragments of row-pair q (rows q*32, q*32+16; k lo/hi halves)
#define RD_AF(DST, tb, q) {                                   \
    DST[0] = LDSA(tb, ab + (q) * 32,      h8);                \
    DST[1] = LDSA(tb, ab + (q) * 32,      32 + h8);           \
    DST[2] = LDSA(tb, ab + (q) * 32 + 16, h8);                \
    DST[3] = LDSA(tb, ab + (q) * 32 + 16, 32 + h8); }

#define RD_BG(tb) {                                                           \
    _Pragma("unroll")                                                         \
    for (int j = 0; j < 4; ++j) {                                             \
        const int bb = wcn * 64 + j * 16 + r;                                 \
        bg[j][0] = LDSB(tb, bb, h8);  bg[j][1] = LDSB(tb, bb, 32 + h8);       \
    } }

#define MFMA_PH(i0, AF)                                                                   \
    __builtin_amdgcn_s_setprio(1);                                                        \
    _Pragma("unroll")                                                                     \
    for (int j = 0; j < 4; ++j) {                                                         \
        acc[i0][j]     = __builtin_amdgcn_mfma_f32_16x16x32_bf16(AF[0], bg[j][0], acc[i0][j], 0, 0, 0);     \
        acc[i0][j]     = __builtin_amdgcn_mfma_f32_16x16x32_bf16(AF[1], bg[j][1], acc[i0][j], 0, 0, 0);     \
        acc[(i0)+1][j] = __builtin_amdgcn_mfma_f32_16x16x32_bf16(AF[2], bg[j][0], acc[(i0)+1][j], 0, 0, 0); \
        acc[(i0)+1][j] = __builtin_amdgcn_mfma_f32_16x16x32_bf16(AF[3], bg[j][1], acc[(i0)+1][j], 0, 0, 0); \
    }                                                                                     \
    __builtin_amdgcn_s_setprio(0);

// One K-tile.  STA: stage A(t+1); STB: stage B(t+2); RDBG: read bg(t+1);
// VM1/VM3: vmcnt count at p1/p3 (-1 = skip).
// lgkm trace (outstanding -> wait): p0: bg8+afX4+afY4 -> 4 (drain bg+afX);
// p1: afY4+afX4 -> 4 (drain afY); p2: afX4+afY4 -> 4 (drain afX);
// p3: afY4 -> 0; then issue bg(t+1)8 which carry into next p0.
#define TILE_BODY(tb, t, STA, STB, RDBG, VM1, VM3)                                        \
  {                                                                                       \
    /* -- p0 -- */                                                                        \
    RD_AF(afX, tb, 0)                                                                     \
    __builtin_amdgcn_sched_barrier(0);                                                    \
    RD_AF(afY, tb, 1)                                                                     \
    if (STA) STAGE_A2(tb ^ 1, 0, (t) + 1)                                                 \
    WAITLGKM4                                                                             \
    MFMA_PH(0, afX)                                                                       \
    /* -- p1 -- */                                                                        \
    RD_AF(afX, tb, 2)                                                                     \
    if (STA) STAGE_A2(tb ^ 1, 1, (t) + 1)                                                 \
    if ((VM1) == 4) { asm volatile("s_waitcnt vmcnt(4)" ::: "memory"); }                  \
    else if ((VM1) == 0) { asm volatile("s_waitcnt vmcnt(0)" ::: "memory"); }             \
    __builtin_amdgcn_s_barrier();  /* B(t+1) landed collectively; Bs WAR fence */         \
    WAITLGKM4                                                                             \
    MFMA_PH(2, afY)                                                                       \
    /* -- p2 -- */                                                                        \
    RD_AF(afY, tb, 3)                                                                     \
    if (STB) STAGE_B2(tb, 0, (t) + 2)                                                     \
    WAITLGKM4                                                                             \
    MFMA_PH(4, afX)                                                                       \
    /* -- p3 -- */                                                                        \
    if (STB) STAGE_B2(tb, 1, (t) + 2)                                                     \
    WAITLGKM0                                                                             \
    MFMA_PH(6, afY)                                                                       \
    if (RDBG) RD_BG((tb) ^ 1)   /* bg(t+1); drains across barrier, retired @ next p0 */   \
    if ((VM3) == 4) { asm volatile("s_waitcnt vmcnt(4)" ::: "memory"); }                  \
    else if ((VM3) == 0) { asm volatile("s_waitcnt vmcnt(0)" ::: "memory"); }             \
    __builtin_amdgcn_s_barrier();  /* A(t+1) landed collectively */                       \
  }

__global__ __launch_bounds__(512, 2) void gemm_pipe3_kernel(
    const ushort* __restrict__ A,    // [M][K] bf16 bits
    const ushort* __restrict__ Bt,   // [N][K] bf16 bits
    const float* __restrict__ bias,  // [N]
    float* __restrict__ C) {         // [M][N]

    __shared__ ushort As[2][256][64];   // 64 KB
    __shared__ ushort Bs[2][256][64];   // 64 KB

    const int tid  = threadIdx.x;
    const int lane = tid & 63;
    const int wv   = tid >> 6;          // wave 0..7
    const int wmr  = wv >> 2;           // 0..1  (M)
    const int wcn  = wv & 3;            // 0..3  (N)
    const int r    = lane & 15;
    const int h8   = (lane >> 4) << 3;  // 0,8,16,24 (ushort col of k-frag)

    // bijective XCD swizzle (nwg = 512)
    const int nbn  = N_TOT / 256;                 // 8
    const int nwg  = (M_TOT / 256) * nbn;         // 512
    const int cpx  = nwg >> 3;
    const int swz  = (blockIdx.x & 7) * cpx + (blockIdx.x >> 3);
    const int brow = (swz / nbn) * 256;
    const int bcol = (swz % nbn) * 256;

    // staging: thread -> row tid>>3 of each 64-row group, 16B at pre-swizzled col
    const int srow = tid >> 3;
    const int scol = (((tid & 7) ^ (srow & 7)) << 3);
    const ushort* Agbase = A  + (size_t)(brow + srow) * K_TOT + scol;
    const ushort* Bgbase = Bt + (size_t)(bcol + srow) * K_TOT + scol;

    const int ab = wmr * 128 + r;       // wave's A row base

    f32x4 acc[8][4];
    const f32x4 zero = {0.f, 0.f, 0.f, 0.f};
    #pragma unroll
    for (int i = 0; i < 8; ++i)
        #pragma unroll
        for (int j = 0; j < 4; ++j) acc[i][j] = zero;

    // ---- prologue: A(0)+B(0)+B(1); vmcnt(4) keeps B(1) in flight; preload bg(0)
    STAGE_A2(0, 0, 0) STAGE_A2(0, 1, 0)
    STAGE_B2(0, 0, 0) STAGE_B2(0, 1, 0)
    STAGE_B2(1, 0, 1) STAGE_B2(1, 1, 1)
    asm volatile("s_waitcnt vmcnt(4)" ::: "memory");
    __builtin_amdgcn_s_barrier();

    bf16x8 afX[4], afY[4];
    bf16x8 bg[4][2];
    RD_BG(0)                                  // bg(0): retires at tile0 p0's lgkm(4)
    __builtin_amdgcn_sched_barrier(0);

    for (int t = 0; t < NT - 2; t += 2) {
        TILE_BODY(0, t,     1, 1, 1, 4, 4)
        TILE_BODY(1, t + 1, 1, 1, 1, 4, 4)
    }
    TILE_BODY(0, NT - 2, 1, 0, 1, 4, 0)    // stage A(31); bg(31); drain all VM
    TILE_BODY(1, NT - 1, 0, 0, 0, -1, -1)  // pure compute

    // ---- epilogue: bias + store (C/D layout: col=lane&15, row=(lane>>4)*4+reg)
    const int hq = (lane >> 4) * 4;
    float bv[4];
    #pragma unroll
    for (int j = 0; j < 4; ++j) bv[j] = bias[bcol + wcn * 64 + j * 16 + r];
    #pragma unroll
    for (int i = 0; i < 8; ++i) {
        const int row0 = brow + wmr * 128 + i * 16 + hq;
        #pragma unroll
        for (int j = 0; j < 4; ++j) {
            const int col = bcol + wcn * 64 + j * 16 + r;
            #pragma unroll
            for (int jj = 0; jj < 4; ++jj)
                C[(size_t)(row0 + jj) * N_TOT + col] = acc[i][j][jj] + bv[j];
        }
    }
}

extern "C" void kernel_launch(void* const* d_in, const int* in_sizes, int n_in,
                              void* d_out, int out_size, void* d_ws, size_t ws_size,
                              hipStream_t stream) {
    const float* x    = (const float*)d_in[0];   // [4,4096,2048]
    const float* wgt  = (const float*)d_in[1];   // [2048,2048]
    const float* bias = (const float*)d_in[2];   // [2048]
    float* out = (float*)d_out;                  // [4,4096,2048]

    ushort* qx = (ushort*)d_ws;                          // 64 MB
    ushort* qw = qx + (size_t)M_TOT * K_TOT;             // 8 MB

    quant_x_kernel<<<(M_TOT * K_TOT / 4) / 256, 256, 0, stream>>>(x, qx);
    quant_w_kernel<<<(64 * 64 * 64) / 256, 256, 0, stream>>>(wgt, qw);
    gemm_pipe3_kernel<<<(M_TOT / 256) * (N_TOT / 256), 512, 0, stream>>>(qx, qw, bias, out);
}